// Round 2
// baseline (758.962 us; speedup 1.0000x reference)
//
#include <hip/hip_runtime.h>
#include <stdint.h>

// Problem constants
#define M_TOTAL 65536       // B*S = 16*4096
#define DIM     1024        // D = K
#define NQKV    3072        // Q|K|V concatenated output cols
#define NHEAD   16
#define HDIM    64

typedef __attribute__((ext_vector_type(8))) _Float16 f16x8;
typedef __attribute__((ext_vector_type(4))) _Float16 f16x4;
typedef __attribute__((ext_vector_type(4))) float    f32x4;

// ---------------------------------------------------------------- prep: x -> f16
__global__ __launch_bounds__(256) void cvt_x_kernel(const float* __restrict__ x,
                                                    _Float16* __restrict__ xh,
                                                    int n4) {
    int i = blockIdx.x * blockDim.x + threadIdx.x;
    int stride = gridDim.x * blockDim.x;
    const float4* x4 = (const float4*)x;
    f16x4* o4 = (f16x4*)xh;
    for (; i < n4; i += stride) {
        float4 v = x4[i];
        f16x4 o;
        o[0] = (_Float16)v.x; o[1] = (_Float16)v.y;
        o[2] = (_Float16)v.z; o[3] = (_Float16)v.w;
        o4[i] = o;
    }
}

// ---------------------------------------------- prep: W (K x N) -> Wt f16 (N x K), 3 mats
__global__ void cvt_w_kernel(const float* __restrict__ Wq,
                             const float* __restrict__ Wk,
                             const float* __restrict__ Wv,
                             _Float16* __restrict__ Wt) {
    __shared__ float tile[32][33];
    int which = blockIdx.z;
    const float* W = (which == 0) ? Wq : (which == 1) ? Wk : Wv;
    int d0 = blockIdx.y * 32, n0 = blockIdx.x * 32;
    int tx = threadIdx.x, ty = threadIdx.y;
    tile[ty][tx] = W[(size_t)(d0 + ty) * DIM + n0 + tx];
    __syncthreads();
    Wt[(size_t)(which * DIM + n0 + ty) * DIM + d0 + tx] = (_Float16)tile[tx][ty];
}

// ---------------------------------------------------------------- prep: bias concat
__global__ __launch_bounds__(256) void bias_kernel(const float* __restrict__ bq,
                                                   const float* __restrict__ bk,
                                                   const float* __restrict__ bv,
                                                   float* __restrict__ bias) {
    int i = blockIdx.x * 256 + threadIdx.x;
    if (i < NQKV)
        bias[i] = (i < 1024) ? bq[i] : (i < 2048) ? bk[i - 1024] : bv[i - 2048];
}

// ---------------------------------------------------------------- fused QKV GEMM
// C[m][n] = sum_k Xh[m][k] * Wt[n][k] + bias[n], written as f16.
// m97 structure: 128x128 tile, BK=32, 4 waves (2x2, each 64x64 = 4x4 frags of 16x16),
// global_load_lds width-16 staging, 2-barrier K-loop.
#define BM 128
#define BN 128
#define BK 32

__global__ __launch_bounds__(256) void qkv_gemm_kernel(const _Float16* __restrict__ Xh,
                                                       const _Float16* __restrict__ Wth,
                                                       const float* __restrict__ bias,
                                                       _Float16* __restrict__ Ch) {
    __shared__ _Float16 As[BM * BK];   // [row m][k] row-major
    __shared__ _Float16 Bs[BN * BK];   // [row n][k] row-major (B^T)

    const int bid  = blockIdx.x;
    const int tn   = bid % (NQKV / BN);      // n-fastest for A-band L2 reuse
    const int tm   = bid / (NQKV / BN);
    const int brow = tm * BM;
    const int bcol = tn * BN;

    const int tid = threadIdx.x;
    const int w   = tid >> 6;
    const int l   = tid & 63;
    const int wr  = w >> 1, wc = w & 1;      // wave computes 64x64 at (wr*64, wc*64)

    const int lrow = l >> 2;                 // staging: row within 16-row group
    const int lcg  = l & 3;                  // staging: 16B column group

    f32x4 acc[4][4] = {};

    for (int k0 = 0; k0 < DIM; k0 += BK) {
        // -------- stage A,B tiles: 2 issues each, 256 lanes x 16B per issue
#pragma unroll
        for (int is = 0; is < 2; ++is) {
            const int r = is * 64 + w * 16 + lrow;           // row within tile
            const _Float16* srcA = Xh  + (size_t)(brow + r) * DIM + k0 + lcg * 8;
            const _Float16* srcB = Wth + (size_t)(bcol + r) * DIM + k0 + lcg * 8;
            _Float16* dstA = As + (is * 64 + w * 16) * BK;   // wave-uniform base
            _Float16* dstB = Bs + (is * 64 + w * 16) * BK;
            __builtin_amdgcn_global_load_lds((const __attribute__((address_space(1))) void*)srcA,
                                             (__attribute__((address_space(3))) void*)dstA, 16, 0, 0);
            __builtin_amdgcn_global_load_lds((const __attribute__((address_space(1))) void*)srcB,
                                             (__attribute__((address_space(3))) void*)dstB, 16, 0, 0);
        }
        __syncthreads();

        // -------- fragments + 16 MFMAs
        f16x8 af[4], bfr[4];
#pragma unroll
        for (int mi = 0; mi < 4; ++mi)
            af[mi] = *(const f16x8*)(As + (wr * 64 + mi * 16 + (l & 15)) * BK + (l >> 4) * 8);
#pragma unroll
        for (int ni = 0; ni < 4; ++ni)
            bfr[ni] = *(const f16x8*)(Bs + (wc * 64 + ni * 16 + (l & 15)) * BK + (l >> 4) * 8);
#pragma unroll
        for (int mi = 0; mi < 4; ++mi)
#pragma unroll
            for (int ni = 0; ni < 4; ++ni)
                acc[mi][ni] = __builtin_amdgcn_mfma_f32_16x16x32_f16(af[mi], bfr[ni], acc[mi][ni], 0, 0, 0);
        __syncthreads();
    }

    // -------- epilogue: + bias, -> f16.  C/D layout: col = l&15, row = (l>>4)*4 + j
#pragma unroll
    for (int ni = 0; ni < 4; ++ni) {
        const int col = bcol + wc * 64 + ni * 16 + (l & 15);
        const float bv = bias[col];
#pragma unroll
        for (int mi = 0; mi < 4; ++mi) {
#pragma unroll
            for (int j = 0; j < 4; ++j) {
                const int row = brow + wr * 64 + mi * 16 + (l >> 4) * 4 + j;
                Ch[(size_t)row * NQKV + col] = (_Float16)(acc[mi][ni][j] + bv);
            }
        }
    }
}

// ---------------------------------------------------------------- per-position attention
// One wave per position. Scores S^T[g][h] = sum_d K[g][d]*Q[h][d] via 2 MFMAs
// (fragments are direct 16B global loads). Wave-parallel softmax over g.
// PV via VALU with V staged in LDS. Output f32, coalesced float4.
__global__ __launch_bounds__(256) void attn_kernel(const _Float16* __restrict__ QKVh,
                                                   float* __restrict__ out) {
    __shared__ _Float16 vlds[4][1024];
    __shared__ float attlds[4][16][16];

    const int w = threadIdx.x >> 6, l = threadIdx.x & 63;
    const size_t p = (size_t)blockIdx.x * 4 + w;
    const _Float16* base = QKVh + p * NQKV;
    const _Float16* qrow = base;
    const _Float16* krow = base + 1024;
    const _Float16* vrow = base + 2048;
    const int h = l & 15;
    const int g4 = (l >> 4) * 4;

    // stage V row (2048 B) into LDS: 32 B per lane
    *(uint4*)&vlds[w][l * 16]     = *(const uint4*)&vrow[l * 16];
    *(uint4*)&vlds[w][l * 16 + 8] = *(const uint4*)&vrow[l * 16 + 8];

    // score fragments: A = K_ (a-row index = l&15 is g), B = Q_^T (b-col index = l&15 is h)
    const int fo = (l & 15) * HDIM + (l >> 4) * 8;
    f16x8 aK0 = *(const f16x8*)&krow[fo];
    f16x8 aK1 = *(const f16x8*)&krow[fo + 32];
    f16x8 bQ0 = *(const f16x8*)&qrow[fo];
    f16x8 bQ1 = *(const f16x8*)&qrow[fo + 32];

    f32x4 sT = {0.f, 0.f, 0.f, 0.f};
    sT = __builtin_amdgcn_mfma_f32_16x16x32_f16(aK0, bQ0, sT, 0, 0, 0);
    sT = __builtin_amdgcn_mfma_f32_16x16x32_f16(aK1, bQ1, sT, 0, 0, 0);
    // lane holds s[h = l&15][g = g4 + i] = sT[i]

    // softmax over g (lanes l, l^16, l^32, l^48 share h)
    float m = fmaxf(fmaxf(sT[0], sT[1]), fmaxf(sT[2], sT[3]));
    m = fmaxf(m, __shfl_xor(m, 16));
    m = fmaxf(m, __shfl_xor(m, 32));
    float e0 = __expf(sT[0] - m), e1 = __expf(sT[1] - m);
    float e2 = __expf(sT[2] - m), e3 = __expf(sT[3] - m);
    float s = e0 + e1 + e2 + e3;
    s += __shfl_xor(s, 16);
    s += __shfl_xor(s, 32);
    const float inv = 1.0f / s;

    float4 att = make_float4(e0 * inv, e1 * inv, e2 * inv, e3 * inv);
    *(float4*)&attlds[w][h][g4] = att;
    __syncthreads();

    // PV: lane computes out[h][dbase .. dbase+15]
    const int dbase = (l >> 4) * 16;
    float acc[16];
#pragma unroll
    for (int c = 0; c < 16; ++c) acc[c] = 0.f;

#pragma unroll
    for (int g = 0; g < 16; ++g) {
        const float a = attlds[w][h][g];
        f16x8 v0 = *(const f16x8*)&vlds[w][g * HDIM + dbase];
        f16x8 v1 = *(const f16x8*)&vlds[w][g * HDIM + dbase + 8];
#pragma unroll
        for (int c = 0; c < 8; ++c) {
            acc[c]     += a * (float)v0[c];
            acc[c + 8] += a * (float)v1[c];
        }
    }

    float* op = out + p * DIM + h * HDIM + dbase;
#pragma unroll
    for (int c = 0; c < 16; c += 4)
        *(float4*)(op + c) = make_float4(acc[c], acc[c + 1], acc[c + 2], acc[c + 3]);
}

// ---------------------------------------------------------------- launch
extern "C" void kernel_launch(void* const* d_in, const int* in_sizes, int n_in,
                              void* d_out, int out_size, void* d_ws, size_t ws_size,
                              hipStream_t stream) {
    const float* x  = (const float*)d_in[0];
    const float* Wq = (const float*)d_in[1];
    const float* bq = (const float*)d_in[2];
    const float* Wk = (const float*)d_in[3];
    const float* bk = (const float*)d_in[4];
    const float* Wv = (const float*)d_in[5];
    const float* bv = (const float*)d_in[6];
    float* out = (float*)d_out;

    char* ws = (char*)d_ws;
    // workspace layout
    //   Xh   : 65536*1024 f16  = 134217728 B
    //   Wth  : 3072*1024  f16  =   6291456 B
    //   bias : 3072       f32  =     12288 B
    //   Ch   : 65536*3072 f16  = 402653184 B   (total ~518 MiB)
    _Float16* Xh  = (_Float16*)ws;
    _Float16* Wth = (_Float16*)(ws + 134217728);
    float*    bias = (float*)(ws + 134217728 + 6291456);
    _Float16* Ch  = (_Float16*)(ws + 134217728 + 6291456 + 12288);

    hipLaunchKernelGGL(cvt_x_kernel, dim3(2048), dim3(256), 0, stream,
                       x, Xh, (M_TOTAL * DIM) / 4);
    hipLaunchKernelGGL(cvt_w_kernel, dim3(32, 32, 3), dim3(32, 32), 0, stream,
                       Wq, Wk, Wv, Wth);
    hipLaunchKernelGGL(bias_kernel, dim3(12), dim3(256), 0, stream,
                       bq, bk, bv, bias);
    hipLaunchKernelGGL(qkv_gemm_kernel, dim3((M_TOTAL / BM) * (NQKV / BN)), dim3(256), 0, stream,
                       Xh, Wth, bias, Ch);
    hipLaunchKernelGGL(attn_kernel, dim3(M_TOTAL / 4), dim3(256), 0, stream,
                       Ch, out);
}

// Round 3
// 638.462 us; speedup vs baseline: 1.1887x; 1.1887x over previous
//
#include <hip/hip_runtime.h>
#include <stdint.h>

// Problem constants
#define M_TOTAL 65536       // B*S = 16*4096
#define DIM     1024        // D = K
#define NQKV    3072        // Q|K|V concatenated output cols
#define NHEAD   16
#define HDIM    64

typedef __attribute__((ext_vector_type(8))) _Float16 f16x8;
typedef __attribute__((ext_vector_type(4))) _Float16 f16x4;
typedef __attribute__((ext_vector_type(4))) float    f32x4;

// ---------------------------------------------------------------- prep: x -> f16
__global__ __launch_bounds__(256) void cvt_x_kernel(const float* __restrict__ x,
                                                    _Float16* __restrict__ xh,
                                                    int n4) {
    int i = blockIdx.x * blockDim.x + threadIdx.x;
    int stride = gridDim.x * blockDim.x;
    const float4* x4 = (const float4*)x;
    f16x4* o4 = (f16x4*)xh;
    for (; i < n4; i += stride) {
        float4 v = x4[i];
        f16x4 o;
        o[0] = (_Float16)v.x; o[1] = (_Float16)v.y;
        o[2] = (_Float16)v.z; o[3] = (_Float16)v.w;
        o4[i] = o;
    }
}

// ---------------------------------------------- prep: W (K x N) -> Wt f16 (N x K), 3 mats
__global__ void cvt_w_kernel(const float* __restrict__ Wq,
                             const float* __restrict__ Wk,
                             const float* __restrict__ Wv,
                             _Float16* __restrict__ Wt) {
    __shared__ float tile[32][33];
    int which = blockIdx.z;
    const float* W = (which == 0) ? Wq : (which == 1) ? Wk : Wv;
    int d0 = blockIdx.y * 32, n0 = blockIdx.x * 32;
    int tx = threadIdx.x, ty = threadIdx.y;
    tile[ty][tx] = W[(size_t)(d0 + ty) * DIM + n0 + tx];
    __syncthreads();
    Wt[(size_t)(which * DIM + n0 + ty) * DIM + d0 + tx] = (_Float16)tile[tx][ty];
}

// ---------------------------------------------------------------- prep: bias concat
__global__ __launch_bounds__(256) void bias_kernel(const float* __restrict__ bq,
                                                   const float* __restrict__ bk,
                                                   const float* __restrict__ bv,
                                                   float* __restrict__ bias) {
    int i = blockIdx.x * 256 + threadIdx.x;
    if (i < NQKV)
        bias[i] = (i < 1024) ? bq[i] : (i < 2048) ? bk[i - 1024] : bv[i - 2048];
}

// ---------------------------------------------------------------- fused QKV GEMM
// 256x256 tile, BK=64, 8 waves (2M x 4N), 8-phase schedule (m201 template):
// per phase {ds_read subtile || 1 half-tile global_load_lds -> barrier -> setprio ->
// 16 MFMA -> setprio -> barrier}, counted vmcnt(4) at phases 3/7 only.
// LDS 128 KiB: A[2][256][64] f16 + B[2][256][64] f16, XOR-swizzled (slot ^= row&7)
// with inverse swizzle applied to the global source (gload_lds writes linearly).

#define LDSA(slot)  ((slot) << 15)
#define LDSB(slot)  (65536 + ((slot) << 15))

// 16 MFMAs: quadrant (MIBASE..+3) x (NIBASE..+1) x ks(0,1)
#define MFMA_Q(MIBASE, NIBASE)                                                  \
    __builtin_amdgcn_s_setprio(1);                                              \
    _Pragma("unroll") for (int mi = 0; mi < 4; ++mi)                            \
    _Pragma("unroll") for (int ni = 0; ni < 2; ++ni)                            \
    _Pragma("unroll") for (int ks = 0; ks < 2; ++ks)                            \
        acc[(MIBASE) + mi][(NIBASE) + ni] = __builtin_amdgcn_mfma_f32_16x16x32_f16( \
            a[mi][ks], b[(NIBASE) + ni][ks], acc[(MIBASE) + mi][(NIBASE) + ni], 0, 0, 0); \
    __builtin_amdgcn_s_setprio(0);

__global__ __launch_bounds__(512, 2) void qkv_gemm_kernel(const _Float16* __restrict__ Xh,
                                                          const _Float16* __restrict__ Wth,
                                                          const float* __restrict__ bias,
                                                          _Float16* __restrict__ Ch) {
    extern __shared__ char smem[];

    // XCD-aware swizzle: 3072 blocks, 3072 % 8 == 0 -> simple bijective form
    const int bid = blockIdx.x;
    const int swz = (bid & 7) * (3072 / 8) + (bid >> 3);
    const int tm  = swz / (NQKV / 256);
    const int tn  = swz % (NQKV / 256);
    const int brow = tm * 256;
    const int bcol = tn * 256;

    const int tid = threadIdx.x;
    const int w   = tid >> 6;          // wave 0..7
    const int l   = tid & 63;
    const int wm  = w >> 2;            // 0..1 -> rows wm*128..+127
    const int wn  = w & 3;             // 0..3 -> cols wn*64..+63

    // ---- staging source (inverse-swizzled): thread covers row (w*8 + l>>3), slot (l&7)^(l>>3)
    const int lrow8 = l >> 3;
    const int lcol8 = (l & 7) ^ lrow8;
    const _Float16* pAsrc = Xh  + (size_t)(brow + w * 8 + lrow8) * DIM + lcol8 * 8;
    const _Float16* pBsrc = Wth + (size_t)(bcol + w * 8 + lrow8) * DIM + lcol8 * 8;

    // one half-tile = 128 rows x 64 cols = 16 KiB = 2 gload issues
    auto stA = [&](int slot, int kt, int half) {
        const _Float16* s = pAsrc + ((size_t)half << 17) + ((size_t)kt << 6);
        char* d = smem + LDSA(slot) + (half << 14) + (w << 10);
        __builtin_amdgcn_global_load_lds((const __attribute__((address_space(1))) void*)s,
                                         (__attribute__((address_space(3))) void*)d, 16, 0, 0);
        __builtin_amdgcn_global_load_lds((const __attribute__((address_space(1))) void*)(s + (1 << 16)),
                                         (__attribute__((address_space(3))) void*)(d + 8192), 16, 0, 0);
    };
    auto stB = [&](int slot, int kt, int half) {
        const _Float16* s = pBsrc + ((size_t)half << 17) + ((size_t)kt << 6);
        char* d = smem + LDSB(slot) + (half << 14) + (w << 10);
        __builtin_amdgcn_global_load_lds((const __attribute__((address_space(1))) void*)s,
                                         (__attribute__((address_space(3))) void*)d, 16, 0, 0);
        __builtin_amdgcn_global_load_lds((const __attribute__((address_space(1))) void*)(s + (1 << 16)),
                                         (__attribute__((address_space(3))) void*)(d + 8192), 16, 0, 0);
    };

    // ---- swizzled LDS reads: physical slot = logical slot ^ (row & 7)
    const int aRowB = ((wm << 7) + (l & 15)) << 7;            // (wm*128 + r16) * 128B
    const int bRowB = 65536 + (((wn << 6) + (l & 15)) << 7);  // Bbase + row*128B
    const int xk0 = (((l >> 4) ^ (l & 7)) << 4);
    const int xk1 = ((((l >> 4) + 4) ^ (l & 7)) << 4);
    auto LDA = [&](int slot, int mi, int ks) -> f16x8 {
        return *(const f16x8*)(smem + (slot << 15) + aRowB + (mi << 11) + (ks ? xk1 : xk0));
    };
    auto LDB = [&](int slot, int ni, int ks) -> f16x8 {
        return *(const f16x8*)(smem + (slot << 15) + bRowB + (ni << 11) + (ks ? xk1 : xk0));
    };

    f32x4 acc[8][4] = {};
    f16x8 a[4][2], b[4][2];

    // ================= prologue: B(0), A(0), B(1); wait all but B(1)
    stB(0, 0, 0); stB(0, 0, 1);
    stA(0, 0, 0); stA(0, 0, 1);
    stB(1, 1, 0); stB(1, 1, 1);
    asm volatile("s_waitcnt vmcnt(4)" ::: "memory");
    __builtin_amdgcn_s_barrier();
    __builtin_amdgcn_sched_barrier(0);

    // ================= main loop: iters 0..6 compute K-tiles 2i, 2i+1
#pragma unroll 1
    for (int i = 0; i < 7; ++i) {
        const int u = 2 * i;
        // ---- PH0 (K-tile u, slot0, quad m0-3 x n0-1) | stage A(u+1) h0 -> slot1
#pragma unroll
        for (int mi = 0; mi < 4; ++mi) { a[mi][0] = LDA(0, mi, 0); a[mi][1] = LDA(0, mi, 1); }
#pragma unroll
        for (int ni = 0; ni < 2; ++ni) { b[ni][0] = LDB(0, ni, 0); b[ni][1] = LDB(0, ni, 1); }
        stA(1, u + 1, 0);
        __builtin_amdgcn_s_barrier();
        MFMA_Q(0, 0)
        __builtin_amdgcn_s_barrier();
        // ---- PH1 (m0-3 x n2-3) | stage A(u+1) h1
        b[2][0] = LDB(0, 2, 0); b[2][1] = LDB(0, 2, 1);
        b[3][0] = LDB(0, 3, 0); b[3][1] = LDB(0, 3, 1);
        stA(1, u + 1, 1);
        __builtin_amdgcn_s_barrier();
        MFMA_Q(0, 2)
        __builtin_amdgcn_s_barrier();
        // ---- PH2 (m4-7 x n0-1) | stage B(u+2) h0 -> slot0
#pragma unroll
        for (int mi = 0; mi < 4; ++mi) { a[mi][0] = LDA(0, mi + 4, 0); a[mi][1] = LDA(0, mi + 4, 1); }
        stB(0, u + 2, 0);
        __builtin_amdgcn_s_barrier();
        MFMA_Q(4, 0)
        __builtin_amdgcn_s_barrier();
        // ---- PH3 (m4-7 x n2-3) | stage B(u+2) h1; publish A(u+1),B(u+1)
        stB(0, u + 2, 1);
        asm volatile("s_waitcnt vmcnt(4)" ::: "memory");
        __builtin_amdgcn_s_barrier();
        __builtin_amdgcn_sched_barrier(0);
        MFMA_Q(4, 2)
        __builtin_amdgcn_s_barrier();
        // ---- PH4 (K-tile u+1, slot1, m0-3 x n0-1) | stage A(u+2) h0 -> slot0
#pragma unroll
        for (int mi = 0; mi < 4; ++mi) { a[mi][0] = LDA(1, mi, 0); a[mi][1] = LDA(1, mi, 1); }
#pragma unroll
        for (int ni = 0; ni < 2; ++ni) { b[ni][0] = LDB(1, ni, 0); b[ni][1] = LDB(1, ni, 1); }
        stA(0, u + 2, 0);
        __builtin_amdgcn_s_barrier();
        MFMA_Q(0, 0)
        __builtin_amdgcn_s_barrier();
        // ---- PH5 (m0-3 x n2-3) | stage A(u+2) h1
        b[2][0] = LDB(1, 2, 0); b[2][1] = LDB(1, 2, 1);
        b[3][0] = LDB(1, 3, 0); b[3][1] = LDB(1, 3, 1);
        stA(0, u + 2, 1);
        __builtin_amdgcn_s_barrier();
        MFMA_Q(0, 2)
        __builtin_amdgcn_s_barrier();
        // ---- PH6 (m4-7 x n0-1) | stage B(u+3) h0 -> slot1
#pragma unroll
        for (int mi = 0; mi < 4; ++mi) { a[mi][0] = LDA(1, mi + 4, 0); a[mi][1] = LDA(1, mi + 4, 1); }
        stB(1, u + 3, 0);
        __builtin_amdgcn_s_barrier();
        MFMA_Q(4, 0)
        __builtin_amdgcn_s_barrier();
        // ---- PH7 (m4-7 x n2-3) | stage B(u+3) h1; publish A(u+2),B(u+2)
        stB(1, u + 3, 1);
        asm volatile("s_waitcnt vmcnt(4)" ::: "memory");
        __builtin_amdgcn_s_barrier();
        __builtin_amdgcn_sched_barrier(0);
        MFMA_Q(4, 2)
        __builtin_amdgcn_s_barrier();
    }

    // ================= peeled last iteration (K-tiles 14, 15)
    {
        // PH0 | stage A(15) h0
#pragma unroll
        for (int mi = 0; mi < 4; ++mi) { a[mi][0] = LDA(0, mi, 0); a[mi][1] = LDA(0, mi, 1); }
#pragma unroll
        for (int ni = 0; ni < 2; ++ni) { b[ni][0] = LDB(0, ni, 0); b[ni][1] = LDB(0, ni, 1); }
        stA(1, 15, 0);
        __builtin_amdgcn_s_barrier();
        MFMA_Q(0, 0)
        __builtin_amdgcn_s_barrier();
        // PH1 | stage A(15) h1
        b[2][0] = LDB(0, 2, 0); b[2][1] = LDB(0, 2, 1);
        b[3][0] = LDB(0, 3, 0); b[3][1] = LDB(0, 3, 1);
        stA(1, 15, 1);
        __builtin_amdgcn_s_barrier();
        MFMA_Q(0, 2)
        __builtin_amdgcn_s_barrier();
        // PH2
#pragma unroll
        for (int mi = 0; mi < 4; ++mi) { a[mi][0] = LDA(0, mi + 4, 0); a[mi][1] = LDA(0, mi + 4, 1); }
        __builtin_amdgcn_s_barrier();
        MFMA_Q(4, 0)
        __builtin_amdgcn_s_barrier();
        // PH3 | drain everything (A(15),B(15) must land)
        asm volatile("s_waitcnt vmcnt(0)" ::: "memory");
        __builtin_amdgcn_s_barrier();
        __builtin_amdgcn_sched_barrier(0);
        MFMA_Q(4, 2)
        __builtin_amdgcn_s_barrier();
        // PH4-7: plain compute of K-tile 15 (slot1)
#pragma unroll
        for (int mi = 0; mi < 4; ++mi) { a[mi][0] = LDA(1, mi, 0); a[mi][1] = LDA(1, mi, 1); }
#pragma unroll
        for (int ni = 0; ni < 2; ++ni) { b[ni][0] = LDB(1, ni, 0); b[ni][1] = LDB(1, ni, 1); }
        __builtin_amdgcn_s_barrier();
        MFMA_Q(0, 0)
        __builtin_amdgcn_s_barrier();
        b[2][0] = LDB(1, 2, 0); b[2][1] = LDB(1, 2, 1);
        b[3][0] = LDB(1, 3, 0); b[3][1] = LDB(1, 3, 1);
        __builtin_amdgcn_s_barrier();
        MFMA_Q(0, 2)
        __builtin_amdgcn_s_barrier();
#pragma unroll
        for (int mi = 0; mi < 4; ++mi) { a[mi][0] = LDA(1, mi + 4, 0); a[mi][1] = LDA(1, mi + 4, 1); }
        __builtin_amdgcn_s_barrier();
        MFMA_Q(4, 0)
        MFMA_Q(4, 2)
    }

    // ================= epilogue: + bias, -> f16. C/D: col = l&15, row = (l>>4)*4 + jj
    const int r4 = (l >> 4) << 2;
#pragma unroll
    for (int ni = 0; ni < 4; ++ni) {
        const int col = bcol + (wn << 6) + (ni << 4) + (l & 15);
        const float bv = bias[col];
#pragma unroll
        for (int mi = 0; mi < 8; ++mi) {
#pragma unroll
            for (int jj = 0; jj < 4; ++jj) {
                const int row = brow + (wm << 7) + (mi << 4) + r4 + jj;
                Ch[(size_t)row * NQKV + col] = (_Float16)(acc[mi][ni][jj] + bv);
            }
        }
    }
}

// ---------------------------------------------------------------- per-position attention
__global__ __launch_bounds__(256) void attn_kernel(const _Float16* __restrict__ QKVh,
                                                   float* __restrict__ out) {
    __shared__ _Float16 vlds[4][1024];
    __shared__ float attlds[4][16][16];

    const int w = threadIdx.x >> 6, l = threadIdx.x & 63;
    const size_t p = (size_t)blockIdx.x * 4 + w;
    const _Float16* base = QKVh + p * NQKV;
    const _Float16* qrow = base;
    const _Float16* krow = base + 1024;
    const _Float16* vrow = base + 2048;
    const int h = l & 15;
    const int g4 = (l >> 4) * 4;

    // stage V row (2048 B) into LDS: 32 B per lane
    *(uint4*)&vlds[w][l * 16]     = *(const uint4*)&vrow[l * 16];
    *(uint4*)&vlds[w][l * 16 + 8] = *(const uint4*)&vrow[l * 16 + 8];

    // score fragments: A = K_ (a-row = g), B = Q_^T (b-col = h)
    const int fo = (l & 15) * HDIM + (l >> 4) * 8;
    f16x8 aK0 = *(const f16x8*)&krow[fo];
    f16x8 aK1 = *(const f16x8*)&krow[fo + 32];
    f16x8 bQ0 = *(const f16x8*)&qrow[fo];
    f16x8 bQ1 = *(const f16x8*)&qrow[fo + 32];

    f32x4 sT = {0.f, 0.f, 0.f, 0.f};
    sT = __builtin_amdgcn_mfma_f32_16x16x32_f16(aK0, bQ0, sT, 0, 0, 0);
    sT = __builtin_amdgcn_mfma_f32_16x16x32_f16(aK1, bQ1, sT, 0, 0, 0);
    // lane holds s[h = l&15][g = g4 + i] = sT[i]

    float m = fmaxf(fmaxf(sT[0], sT[1]), fmaxf(sT[2], sT[3]));
    m = fmaxf(m, __shfl_xor(m, 16));
    m = fmaxf(m, __shfl_xor(m, 32));
    float e0 = __expf(sT[0] - m), e1 = __expf(sT[1] - m);
    float e2 = __expf(sT[2] - m), e3 = __expf(sT[3] - m);
    float s = e0 + e1 + e2 + e3;
    s += __shfl_xor(s, 16);
    s += __shfl_xor(s, 32);
    const float inv = 1.0f / s;

    float4 att = make_float4(e0 * inv, e1 * inv, e2 * inv, e3 * inv);
    *(float4*)&attlds[w][h][g4] = att;
    __syncthreads();

    const int dbase = (l >> 4) * 16;
    float acc[16];
#pragma unroll
    for (int c = 0; c < 16; ++c) acc[c] = 0.f;

#pragma unroll
    for (int g = 0; g < 16; ++g) {
        const float av = attlds[w][h][g];
        f16x8 v0 = *(const f16x8*)&vlds[w][g * HDIM + dbase];
        f16x8 v1 = *(const f16x8*)&vlds[w][g * HDIM + dbase + 8];
#pragma unroll
        for (int c = 0; c < 8; ++c) {
            acc[c]     += av * (float)v0[c];
            acc[c + 8] += av * (float)v1[c];
        }
    }

    float* op = out + p * DIM + h * HDIM + dbase;
#pragma unroll
    for (int c = 0; c < 16; c += 4)
        *(float4*)(op + c) = make_float4(acc[c], acc[c + 1], acc[c + 2], acc[c + 3]);
}

// ---------------------------------------------------------------- launch
extern "C" void kernel_launch(void* const* d_in, const int* in_sizes, int n_in,
                              void* d_out, int out_size, void* d_ws, size_t ws_size,
                              hipStream_t stream) {
    const float* x  = (const float*)d_in[0];
    const float* Wq = (const float*)d_in[1];
    const float* bq = (const float*)d_in[2];
    const float* Wk = (const float*)d_in[3];
    const float* bk = (const float*)d_in[4];
    const float* Wv = (const float*)d_in[5];
    const float* bv = (const float*)d_in[6];
    float* out = (float*)d_out;

    char* ws = (char*)d_ws;
    _Float16* Xh  = (_Float16*)ws;
    _Float16* Wth = (_Float16*)(ws + 134217728);
    float*    bias = (float*)(ws + 134217728 + 6291456);
    _Float16* Ch  = (_Float16*)(ws + 134217728 + 6291456 + 12288);

    // allow 128 KiB dynamic LDS (gfx950 has 160 KiB/CU)
    static int lds_attr_set = 0;
    (void)hipFuncSetAttribute((const void*)qkv_gemm_kernel,
                              hipFuncAttributeMaxDynamicSharedMemorySize, 131072);

    hipLaunchKernelGGL(cvt_x_kernel, dim3(2048), dim3(256), 0, stream,
                       x, Xh, (M_TOTAL * DIM) / 4);
    hipLaunchKernelGGL(cvt_w_kernel, dim3(32, 32, 3), dim3(32, 32), 0, stream,
                       Wq, Wk, Wv, Wth);
    hipLaunchKernelGGL(bias_kernel, dim3(12), dim3(256), 0, stream,
                       bq, bk, bv, bias);
    hipLaunchKernelGGL(qkv_gemm_kernel, dim3((M_TOTAL / 256) * (NQKV / 256)), dim3(512), 131072, stream,
                       Xh, Wth, bias, Ch);
    hipLaunchKernelGGL(attn_kernel, dim3(M_TOTAL / 4), dim3(256), 0, stream,
                       Ch, out);
}